// Round 5
// baseline (422.020 us; speedup 1.0000x reference)
//
#include <hip/hip_runtime.h>

typedef unsigned short ushort_t;
typedef unsigned int uint32;
typedef __attribute__((ext_vector_type(8))) short short8;
typedef __attribute__((ext_vector_type(4))) float f32x4;

#define LDS_LOAD16(gptr, lptr)                                                             \
  __builtin_amdgcn_global_load_lds((const __attribute__((address_space(1))) uint32*)(gptr),\
                                   (__attribute__((address_space(3))) uint32*)(lptr),      \
                                   16, 0, 0)

__device__ __forceinline__ ushort_t f2b(float f) {
  uint32 u = __builtin_bit_cast(uint32, f);
  u += 0x7fffu + ((u >> 16) & 1u);   // RNE
  return (ushort_t)(u >> 16);
}
__device__ __forceinline__ float b2f(ushort_t b) {
  uint32 u = ((uint32)b) << 16;
  return __builtin_bit_cast(float, u);
}
__device__ __forceinline__ uint32 pk2(float a, float b) {
  return (uint32)f2b(a) | ((uint32)f2b(b) << 16);
}
__device__ __forceinline__ int swz8(int r) { return (r ^ (r >> 3)) & 7; }

constexpr size_t E = (size_t)2048 * 2048;

// ---------------- fused fp32 -> bf16 convert (all 5 tensors) ----------------
__global__ __launch_bounds__(256) void k_cvt5(const float* __restrict__ a0, const float* __restrict__ a1,
                                              const float* __restrict__ a2, const float* __restrict__ a3,
                                              const float* __restrict__ a4, ushort_t* __restrict__ out) {
  const float* srcs[5] = {a0, a1, a2, a3, a4};
  const float* s = srcs[blockIdx.y];
  size_t i = ((size_t)blockIdx.x * 256 + threadIdx.x) * 4;
  float4 v = *(const float4*)(s + i);
  ushort4 o;
  o.x = f2b(v.x); o.y = f2b(v.y); o.z = f2b(v.z); o.w = f2b(v.w);
  *(ushort4*)(out + (size_t)blockIdx.y * E + i) = o;
}

// ---------------- QKV GEMM, NO LDS: direct global->fragment loads ----------------
// Each wave owns a 64x64 C-tile; A/B fragments are 16-row x 64B-contiguous global
// loads (immediate offsets off 8 per-lane base pointers). No barriers anywhere in
// the K-loop -> loads interleave with MFMA via graduated vmcnt. XCD swizzle: all
// col/z blocks of an A row-panel pair land on one XCD (lin%8) for L2 residency.
// z=0 -> Qm (rope + 1/sqrt(dh) scale), z=1 -> Km (rope), z=2 -> Vt (transposed).
__global__ __launch_bounds__(256) void k_gemm_qkv(const ushort_t* __restrict__ A,
                                                  const ushort_t* __restrict__ B0,
                                                  const ushort_t* __restrict__ B1,
                                                  const ushort_t* __restrict__ B2,
                                                  ushort_t* __restrict__ Qm,
                                                  ushort_t* __restrict__ Km,
                                                  ushort_t* __restrict__ Vt,
                                                  const int* __restrict__ pos) {
  const int tid = threadIdx.x;
  const int lane = tid & 63, wave = tid >> 6;
  const int quad = lane >> 4, l16 = lane & 15;
  const int wm = wave >> 1, wn = wave & 1;

  // decode swizzled block coords: xcd = lin%8 hosts rows {xcd, xcd+8} x all col,z
  const int lin = blockIdx.x + (blockIdx.y << 4) + (blockIdx.z << 8);
  const int s = lin >> 3;
  const int row = (lin & 7) | ((s & 1) << 3);
  const int rest = s >> 1;
  const int col = rest & 15;
  const int z = rest >> 4;
  const ushort_t* Bp = (z == 0) ? B0 : (z == 1) ? B1 : B2;
  const size_t row0 = (size_t)row * 128, col0 = (size_t)col * 128;

  int g[4];
#pragma unroll
  for (int j = 0; j < 4; ++j) g[j] = (j & 1) + ((j >> 1) << 2) + wn * 2;  // {0,1,4,5}/{2,3,6,7}

  const ushort_t* abase[4];
  const ushort_t* bbase[4];
#pragma unroll
  for (int i = 0; i < 4; ++i)
    abase[i] = A + (row0 + wm * 64 + i * 16 + l16) * 2048 + quad * 8;
#pragma unroll
  for (int j = 0; j < 4; ++j)
    bbase[j] = Bp + (col0 + g[j] * 16 + l16) * 2048 + quad * 8;

  f32x4 zero = {0.f, 0.f, 0.f, 0.f};
  f32x4 acc[4][4];
#pragma unroll
  for (int i = 0; i < 4; ++i)
#pragma unroll
    for (int j = 0; j < 4; ++j) acc[i][j] = zero;

#pragma unroll 4
  for (int kt = 0; kt < 64; ++kt) {
    short8 a[4], b[4];
#pragma unroll
    for (int i = 0; i < 4; ++i) a[i] = *(const short8*)(abase[i] + kt * 32);
#pragma unroll
    for (int j = 0; j < 4; ++j) b[j] = *(const short8*)(bbase[j] + kt * 32);
#pragma unroll
    for (int i = 0; i < 4; ++i)
#pragma unroll
      for (int j = 0; j < 4; ++j)
        acc[i][j] = __builtin_amdgcn_mfma_f32_16x16x32_bf16(a[i], b[j], acc[i][j], 0, 0, 0);
  }

  if (z < 2) {
    ushort_t* C = z ? Km : Qm;
    const float mul = z ? 1.0f : 0.08838834764831845f;  // fold 1/sqrt(128) into Q
#pragma unroll
    for (int i = 0; i < 4; ++i)
#pragma unroll
      for (int r = 0; r < 4; ++r) {
        size_t rr = row0 + wm * 64 + i * 16 + quad * 4 + r;
        float pt = (float)pos[rr];
        size_t rowoff = rr * 2048 + col0;
#pragma unroll
        for (int j = 0; j < 2; ++j) {
          int f = g[j] * 16 + l16;   // f in [0,64)
          float ang = pt * __expf(-0.14391156831212787f * (float)f);
          float sn, cs;
          __sincosf(ang, &sn, &cs);
          cs *= mul; sn *= mul;
          float q0 = acc[i][j][r], q1 = acc[i][j + 2][r];
          C[rowoff + f]      = f2b(q0 * cs - q1 * sn);
          C[rowoff + f + 64] = f2b(q1 * cs + q0 * sn);
        }
      }
  } else {
#pragma unroll
    for (int i = 0; i < 4; ++i)
#pragma unroll
      for (int j = 0; j < 4; ++j) {
        size_t cc = col0 + g[j] * 16 + l16;
        size_t rowb = row0 + wm * 64 + i * 16 + quad * 4;
        ushort4 ov;
        ov.x = f2b(acc[i][j][0]); ov.y = f2b(acc[i][j][1]);
        ov.z = f2b(acc[i][j][2]); ov.w = f2b(acc[i][j][3]);
        *(ushort4*)&Vt[cc * 2048 + rowb] = ov;
      }
  }
}

// ---------------- flash attention: key-split waves, no K/V LDS, no loop barriers ----------------
// Q arrives pre-scaled by 1/sqrt(dh). grid 512: 64 q-rows x 16 heads, XCD-clustered.
__global__ __launch_bounds__(256, 2) void k_attn(const ushort_t* __restrict__ Q,
                                                 const ushort_t* __restrict__ Kg,
                                                 const ushort_t* __restrict__ Vt,
                                                 ushort_t* __restrict__ O) {
  __shared__ ushort_t Qs[64 * 128];      // swizzled: row r, chunk c stored at c ^ (r&15)
  __shared__ float Rbuf[4][16][132];
  __shared__ float Lred[4][4][16];
  const int tid = threadIdx.x;
  const int lane = tid & 63, wave = tid >> 6;
  const int quad = lane >> 4, l16 = lane & 15;
  const int bid = blockIdx.x;
  const int head = ((bid & 7) << 1) + ((bid >> 3) >> 5);
  const int qt = (bid >> 3) & 31;

#pragma unroll
  for (int j = 0; j < 4; ++j) {
    int s = tid + 256 * j;
    int r = s >> 4, p = s & 15;
    LDS_LOAD16(Q + (size_t)(qt * 64 + r) * 2048 + head * 128 + ((p ^ (r & 15)) * 8), &Qs[s * 8]);
  }
  __syncthreads();

  f32x4 zero = {0.f, 0.f, 0.f, 0.f};
  f32x4 oacc[4][8];
#pragma unroll
  for (int qg = 0; qg < 4; ++qg)
#pragma unroll
    for (int ns = 0; ns < 8; ++ns) oacc[qg][ns] = zero;
  float l_acc[4] = {0.f, 0.f, 0.f, 0.f};
  const int srcA = ((quad & 1) << 5) | l16;
  const int srcB = srcA + 16;
  const bool hiq = quad >= 2;

  const ushort_t* Kbase = Kg + (size_t)head * 128;
  const ushort_t* Vbase = Vt + (size_t)head * 128 * 2048;

  for (int it = 0; it < 16; ++it) {
    const int kb = it * 128 + wave * 32;

    short8 kf[2][4];
#pragma unroll
    for (int kg = 0; kg < 2; ++kg)
#pragma unroll
      for (int kk = 0; kk < 4; ++kk)
        kf[kg][kk] = *(const short8*)&Kbase[(size_t)(kb + kg * 16 + l16) * 2048 + kk * 32 + quad * 8];

    uint32 pp[4][2][2];
#pragma unroll
    for (int qg = 0; qg < 4; ++qg) {
      short8 qa[4];
#pragma unroll
      for (int kk = 0; kk < 4; ++kk)
        qa[kk] = *(const short8*)&Qs[((qg * 16 + l16) * 16 + ((kk * 4 + quad) ^ l16)) * 8];
      f32x4 s0 = zero, s1 = zero;
#pragma unroll
      for (int kk = 0; kk < 4; ++kk) {
        s0 = __builtin_amdgcn_mfma_f32_16x16x32_bf16(kf[0][kk], qa[kk], s0, 0, 0, 0);
        s1 = __builtin_amdgcn_mfma_f32_16x16x32_bf16(kf[1][kk], qa[kk], s1, 0, 0, 0);
      }
      float p00 = __expf(s0[0]), p01 = __expf(s0[1]);
      float p02 = __expf(s0[2]), p03 = __expf(s0[3]);
      float p10 = __expf(s1[0]), p11 = __expf(s1[1]);
      float p12 = __expf(s1[2]), p13 = __expf(s1[3]);
      l_acc[qg] += ((p00 + p01) + (p02 + p03)) + ((p10 + p11) + (p12 + p13));
      pp[qg][0][0] = pk2(p00, p01);
      pp[qg][0][1] = pk2(p02, p03);
      pp[qg][1][0] = pk2(p10, p11);
      pp[qg][1][1] = pk2(p12, p13);
    }

    short8 pb[4];
#pragma unroll
    for (int qg = 0; qg < 4; ++qg) {
      uint32 a0 = (uint32)__shfl((int)pp[qg][0][0], srcA, 64);
      uint32 b0 = (uint32)__shfl((int)pp[qg][1][0], srcA, 64);
      uint32 a1 = (uint32)__shfl((int)pp[qg][0][1], srcA, 64);
      uint32 b1 = (uint32)__shfl((int)pp[qg][1][1], srcA, 64);
      uint32 a2 = (uint32)__shfl((int)pp[qg][0][0], srcB, 64);
      uint32 b2 = (uint32)__shfl((int)pp[qg][1][0], srcB, 64);
      uint32 a3 = (uint32)__shfl((int)pp[qg][0][1], srcB, 64);
      uint32 b3 = (uint32)__shfl((int)pp[qg][1][1], srcB, 64);
      union { uint32 u[4]; short8 v; } cvt;
      cvt.u[0] = hiq ? b0 : a0;
      cvt.u[1] = hiq ? b1 : a1;
      cvt.u[2] = hiq ? b2 : a2;
      cvt.u[3] = hiq ? b3 : a3;
      pb[qg] = cvt.v;
    }

#pragma unroll
    for (int ns = 0; ns < 8; ++ns) {
      const short8 vf = *(const short8*)&Vbase[(size_t)(ns * 16 + l16) * 2048 + kb + quad * 8];
#pragma unroll
      for (int qg = 0; qg < 4; ++qg)
        oacc[qg][ns] = __builtin_amdgcn_mfma_f32_16x16x32_bf16(vf, pb[qg], oacc[qg][ns], 0, 0, 0);
    }
  }

#pragma unroll
  for (int qg = 0; qg < 4; ++qg) {
    float l = l_acc[qg];
    l += __shfl_xor(l, 16, 64);
    l += __shfl_xor(l, 32, 64);
    l_acc[qg] = l;
  }
  if (quad == 0) {
#pragma unroll
    for (int qg = 0; qg < 4; ++qg) Lred[wave][qg][l16] = l_acc[qg];
  }

  const int tq = tid >> 4;
  const int td = (tid & 15) * 8;
  for (int qg = 0; qg < 4; ++qg) {
    __syncthreads();
#pragma unroll
    for (int ns = 0; ns < 8; ++ns)
      *(f32x4*)&Rbuf[wave][l16][ns * 16 + quad * 4] = oacc[qg][ns];
    __syncthreads();
    float lt = Lred[0][qg][tq] + Lred[1][qg][tq] + Lred[2][qg][tq] + Lred[3][qg][tq];
    float inv = 1.0f / lt;
    f32x4 sA = zero, sB = zero;
#pragma unroll
    for (int w = 0; w < 4; ++w) {
      sA += *(const f32x4*)&Rbuf[w][tq][td];
      sB += *(const f32x4*)&Rbuf[w][tq][td + 4];
    }
    ushort4 o1, o2;
    o1.x = f2b(sA[0] * inv); o1.y = f2b(sA[1] * inv);
    o1.z = f2b(sA[2] * inv); o1.w = f2b(sA[3] * inv);
    o2.x = f2b(sB[0] * inv); o2.y = f2b(sB[1] * inv);
    o2.z = f2b(sB[2] * inv); o2.w = f2b(sB[3] * inv);
    size_t orow = (size_t)(qt * 64 + qg * 16 + tq) * 2048 + head * 128 + td;
    *(ushort4*)&O[orow] = o1;
    *(ushort4*)&O[orow + 4] = o2;
  }
}

// ---------------- Wo GEMM-BT: 128x64 tile, BK=64, fp32 output ----------------
__global__ __launch_bounds__(256) void k_gemm_wo(const ushort_t* __restrict__ A,
                                                 const ushort_t* __restrict__ B,
                                                 float* __restrict__ C) {
  __shared__ ushort_t As[128 * 64];
  __shared__ ushort_t Bs[64 * 64];
  const int tid = threadIdx.x;
  const int lane = tid & 63, wave = tid >> 6;
  const int quad = lane >> 4, l16 = lane & 15;
  const int wm = wave >> 1, wn = wave & 1;
  const size_t row0 = (size_t)blockIdx.y * 128, col0 = (size_t)blockIdx.x * 64;

  f32x4 zero = {0.f, 0.f, 0.f, 0.f};
  f32x4 acc[4][2];
#pragma unroll
  for (int i = 0; i < 4; ++i)
#pragma unroll
    for (int j = 0; j < 2; ++j) acc[i][j] = zero;

  for (int kt = 0; kt < 32; ++kt) {
#pragma unroll
    for (int j2 = 0; j2 < 4; ++j2) {
      int c = tid + 256 * j2;
      int r = c >> 3, p = c & 7;
      LDS_LOAD16(A + (row0 + r) * 2048 + kt * 64 + (p ^ swz8(r)) * 8, &As[c * 8]);
    }
#pragma unroll
    for (int j2 = 0; j2 < 2; ++j2) {
      int c = tid + 256 * j2;
      int r = c >> 3, p = c & 7;
      LDS_LOAD16(B + (col0 + r) * 2048 + kt * 64 + (p ^ swz8(r)) * 8, &Bs[c * 8]);
    }
    __syncthreads();
    short8 a[4][2], b[2][2];
#pragma unroll
    for (int i = 0; i < 4; ++i) {
      int ra = wm * 64 + i * 16 + l16;
#pragma unroll
      for (int kk = 0; kk < 2; ++kk)
        a[i][kk] = *(const short8*)&As[(ra * 8 + ((kk * 4 + quad) ^ swz8(ra))) * 8];
    }
#pragma unroll
    for (int j = 0; j < 2; ++j) {
      int rb = wn * 32 + j * 16 + l16;
#pragma unroll
      for (int kk = 0; kk < 2; ++kk)
        b[j][kk] = *(const short8*)&Bs[(rb * 8 + ((kk * 4 + quad) ^ swz8(rb))) * 8];
    }
#pragma unroll
    for (int kk = 0; kk < 2; ++kk)
#pragma unroll
      for (int i = 0; i < 4; ++i)
#pragma unroll
        for (int j = 0; j < 2; ++j)
          acc[i][j] = __builtin_amdgcn_mfma_f32_16x16x32_bf16(a[i][kk], b[j][kk], acc[i][j], 0, 0, 0);
    __syncthreads();
  }

#pragma unroll
  for (int i = 0; i < 4; ++i)
#pragma unroll
    for (int j = 0; j < 2; ++j)
#pragma unroll
      for (int r = 0; r < 4; ++r) {
        size_t row = row0 + wm * 64 + i * 16 + quad * 4 + r;
        size_t col = col0 + wn * 32 + j * 16 + l16;
        C[row * 2048 + col] = acc[i][j][r];
      }
}

extern "C" void kernel_launch(void* const* d_in, const int* in_sizes, int n_in,
                              void* d_out, int out_size, void* d_ws, size_t ws_size,
                              hipStream_t stream) {
  const float* X  = (const float*)d_in[0];
  const float* wq = (const float*)d_in[1];
  const float* wk = (const float*)d_in[2];
  const float* wv = (const float*)d_in[3];
  const float* wo = (const float*)d_in[4];
  const int*  pos = (const int*)d_in[5];
  float* out = (float*)d_out;

  if (ws_size < 9 * E * sizeof(ushort_t)) return;  // need 72 MB scratch

  ushort_t* Xb  = (ushort_t*)d_ws;
  ushort_t* Wqb = Xb + E;
  ushort_t* Wkb = Xb + 2 * E;
  ushort_t* Wvb = Xb + 3 * E;
  ushort_t* Wob = Xb + 4 * E;
  ushort_t* Qm  = Xb + 5 * E;
  ushort_t* Km  = Xb + 6 * E;
  ushort_t* Vtm = Xb + 7 * E;
  ushort_t* Om  = Xb + 8 * E;

  dim3 b256(256);
  k_cvt5<<<dim3(4096, 5), b256, 0, stream>>>(X, wq, wk, wv, wo, Xb);
  k_gemm_qkv<<<dim3(16, 16, 3), b256, 0, stream>>>(Xb, Wqb, Wkb, Wvb, Qm, Km, Vtm, pos);
  k_attn<<<512, b256, 0, stream>>>(Qm, Km, Vtm, Om);
  k_gemm_wo<<<dim3(32, 16), b256, 0, stream>>>(Om, Wob, out);
}

// Round 6
// 365.127 us; speedup vs baseline: 1.1558x; 1.1558x over previous
//
#include <hip/hip_runtime.h>

typedef unsigned short ushort_t;
typedef unsigned int uint32;
typedef __attribute__((ext_vector_type(8))) short short8;
typedef __attribute__((ext_vector_type(4))) float f32x4;
typedef __attribute__((ext_vector_type(2))) uint32 u32x2;

#define LDS_LOAD16(gptr, lptr)                                                             \
  __builtin_amdgcn_global_load_lds((const __attribute__((address_space(1))) uint32*)(gptr),\
                                   (__attribute__((address_space(3))) uint32*)(lptr),      \
                                   16, 0, 0)

__device__ __forceinline__ ushort_t f2b(float f) {
  uint32 u = __builtin_bit_cast(uint32, f);
  u += 0x7fffu + ((u >> 16) & 1u);   // RNE
  return (ushort_t)(u >> 16);
}
__device__ __forceinline__ float b2f(ushort_t b) {
  uint32 u = ((uint32)b) << 16;
  return __builtin_bit_cast(float, u);
}
__device__ __forceinline__ uint32 pk2(float a, float b) {
  return (uint32)f2b(a) | ((uint32)f2b(b) << 16);
}
__device__ __forceinline__ int swz8(int r) { return (r ^ (r >> 3)) & 7; }

constexpr size_t E = (size_t)2048 * 2048;

// ---------------- fused fp32 -> bf16 convert (all 5 tensors) ----------------
__global__ __launch_bounds__(256) void k_cvt5(const float* __restrict__ a0, const float* __restrict__ a1,
                                              const float* __restrict__ a2, const float* __restrict__ a3,
                                              const float* __restrict__ a4, ushort_t* __restrict__ out) {
  const float* srcs[5] = {a0, a1, a2, a3, a4};
  const float* s = srcs[blockIdx.y];
  size_t i = ((size_t)blockIdx.x * 256 + threadIdx.x) * 4;
  float4 v = *(const float4*)(s + i);
  ushort4 o;
  o.x = f2b(v.x); o.y = f2b(v.y); o.z = f2b(v.z); o.w = f2b(v.w);
  *(ushort4*)(out + (size_t)blockIdx.y * E + i) = o;
}

// ---------------- fused QKV GEMM-BT, BK=64, fused RoPE epilogue (R4 known-good) ----------------
// z=0 -> Qm (rope + 1/sqrt(dh) scale), z=1 -> Km (rope), z=2 -> Vt (transposed write)
__global__ __launch_bounds__(256) void k_gemm_qkv(const ushort_t* __restrict__ A,
                                                  const ushort_t* __restrict__ B0,
                                                  const ushort_t* __restrict__ B1,
                                                  const ushort_t* __restrict__ B2,
                                                  ushort_t* __restrict__ Qm,
                                                  ushort_t* __restrict__ Km,
                                                  ushort_t* __restrict__ Vt,
                                                  const int* __restrict__ pos) {
  __shared__ ushort_t As[128 * 64];
  __shared__ ushort_t Bs[128 * 64];
  const int tid = threadIdx.x;
  const int lane = tid & 63, wave = tid >> 6;
  const int quad = lane >> 4, l16 = lane & 15;
  const int wm = wave >> 1, wn = wave & 1;
  const int z = blockIdx.z;
  const ushort_t* Bp = (z == 0) ? B0 : (z == 1) ? B1 : B2;
  const size_t row0 = (size_t)blockIdx.y * 128, col0 = (size_t)blockIdx.x * 128;

  int g[4];
#pragma unroll
  for (int j = 0; j < 4; ++j) g[j] = (j & 1) + ((j >> 1) << 2) + wn * 2;  // {0,1,4,5}/{2,3,6,7}

  f32x4 zero = {0.f, 0.f, 0.f, 0.f};
  f32x4 acc[4][4];
#pragma unroll
  for (int i = 0; i < 4; ++i)
#pragma unroll
    for (int j = 0; j < 4; ++j) acc[i][j] = zero;

  for (int kt = 0; kt < 32; ++kt) {
#pragma unroll
    for (int j2 = 0; j2 < 4; ++j2) {
      int c = tid + 256 * j2;            // 1024 chunks of 16B per matrix
      int r = c >> 3, p = c & 7;
      int sc = (p ^ swz8(r)) * 8;
      LDS_LOAD16(A + (row0 + r) * 2048 + kt * 64 + sc, &As[c * 8]);
      LDS_LOAD16(Bp + (col0 + r) * 2048 + kt * 64 + sc, &Bs[c * 8]);
    }
    __syncthreads();
    short8 a[4][2], b[4][2];
#pragma unroll
    for (int i = 0; i < 4; ++i) {
      int ra = wm * 64 + i * 16 + l16;
#pragma unroll
      for (int kk = 0; kk < 2; ++kk)
        a[i][kk] = *(const short8*)&As[(ra * 8 + ((kk * 4 + quad) ^ swz8(ra))) * 8];
    }
#pragma unroll
    for (int j = 0; j < 4; ++j) {
      int rb = g[j] * 16 + l16;
#pragma unroll
      for (int kk = 0; kk < 2; ++kk)
        b[j][kk] = *(const short8*)&Bs[(rb * 8 + ((kk * 4 + quad) ^ swz8(rb))) * 8];
    }
#pragma unroll
    for (int kk = 0; kk < 2; ++kk)
#pragma unroll
      for (int i = 0; i < 4; ++i)
#pragma unroll
        for (int j = 0; j < 4; ++j)
          acc[i][j] = __builtin_amdgcn_mfma_f32_16x16x32_bf16(a[i][kk], b[j][kk], acc[i][j], 0, 0, 0);
    __syncthreads();
  }

  if (z < 2) {
    ushort_t* C = z ? Km : Qm;
    const float mul = z ? 1.0f : 0.08838834764831845f;  // fold 1/sqrt(128) into Q
#pragma unroll
    for (int i = 0; i < 4; ++i)
#pragma unroll
      for (int r = 0; r < 4; ++r) {
        size_t row = row0 + wm * 64 + i * 16 + quad * 4 + r;
        float pt = (float)pos[row];
        size_t rowoff = row * 2048 + col0;
#pragma unroll
        for (int j = 0; j < 2; ++j) {
          int f = g[j] * 16 + l16;   // f in [0,64)
          float ang = pt * __expf(-0.14391156831212787f * (float)f);
          float sn, cs;
          __sincosf(ang, &sn, &cs);
          cs *= mul; sn *= mul;
          float q0 = acc[i][j][r], q1 = acc[i][j + 2][r];
          C[rowoff + f]      = f2b(q0 * cs - q1 * sn);
          C[rowoff + f + 64] = f2b(q1 * cs + q0 * sn);
        }
      }
  } else {
#pragma unroll
    for (int i = 0; i < 4; ++i)
#pragma unroll
      for (int j = 0; j < 4; ++j) {
        size_t col = col0 + g[j] * 16 + l16;
        size_t rowb = row0 + wm * 64 + i * 16 + quad * 4;
        ushort4 ov;
        ov.x = f2b(acc[i][j][0]); ov.y = f2b(acc[i][j][1]);
        ov.z = f2b(acc[i][j][2]); ov.w = f2b(acc[i][j][3]);
        *(ushort4*)&Vt[col * 2048 + rowb] = ov;
      }
  }
}

// ---------------- flash attention: key-split waves, P-transpose via wave-private LDS ----------------
// Q arrives pre-scaled by 1/sqrt(dh). grid 512: 64 q-rows x 16 heads, XCD-clustered.
// Per-iter P^T (MFMA C-layout) -> B-operand layout through a wave-private LDS region
// (no barrier: same-wave lgkmcnt ordering). 80B row stride = pigeonhole-minimum banking.
__global__ __launch_bounds__(256) void k_attn(const ushort_t* __restrict__ Q,
                                              const ushort_t* __restrict__ Kg,
                                              const ushort_t* __restrict__ Vt,
                                              ushort_t* __restrict__ O) {
  __shared__ uint32 smem[9216 + 256];   // 36 KB (Qs 16K + Pbuf 20K) + Lred 1K
  ushort_t* Qs  = (ushort_t*)smem;      // 64 x 128 bf16, swizzled: chunk c at c ^ (r&15)
  uint32*   Pbf = smem + 4096;          // 4 waves x 64 rows x 20 dwords (80 B stride)
  float*    Lred = (float*)(smem + 9216);  // [wave][qg][l16]
  float*    Rbuf = (float*)smem;        // epilogue alias: [wave][16][132] = 8448 dw <= 9216

  const int tid = threadIdx.x;
  const int lane = tid & 63, wave = tid >> 6;
  const int quad = lane >> 4, l16 = lane & 15;
  const int bid = blockIdx.x;
  const int head = ((bid & 7) << 1) + ((bid >> 3) >> 5);
  const int qt = (bid >> 3) & 31;

#pragma unroll
  for (int j = 0; j < 4; ++j) {
    int s = tid + 256 * j;
    int r = s >> 4, p = s & 15;
    LDS_LOAD16(Q + (size_t)(qt * 64 + r) * 2048 + head * 128 + ((p ^ (r & 15)) * 8), &Qs[s * 8]);
  }
  __syncthreads();

  f32x4 zero = {0.f, 0.f, 0.f, 0.f};
  f32x4 oacc[4][8];
#pragma unroll
  for (int qg = 0; qg < 4; ++qg)
#pragma unroll
    for (int ns = 0; ns < 8; ++ns) oacc[qg][ns] = zero;
  float l_acc[4] = {0.f, 0.f, 0.f, 0.f};

  const ushort_t* Kbase = Kg + (size_t)head * 128;
  const ushort_t* Vbase = Vt + (size_t)head * 128 * 2048;
  uint32* pw = Pbf + wave * 1280;

  for (int it = 0; it < 16; ++it) {
    const int kb = it * 128 + wave * 32;

    short8 kf[2][4];
#pragma unroll
    for (int kg = 0; kg < 2; ++kg)
#pragma unroll
      for (int kk = 0; kk < 4; ++kk)
        kf[kg][kk] = *(const short8*)&Kbase[(size_t)(kb + kg * 16 + l16) * 2048 + kk * 32 + quad * 8];

#pragma unroll
    for (int qg = 0; qg < 4; ++qg) {
      short8 qa[4];
#pragma unroll
      for (int kk = 0; kk < 4; ++kk)
        qa[kk] = *(const short8*)&Qs[((qg * 16 + l16) * 16 + ((kk * 4 + quad) ^ l16)) * 8];
      f32x4 s0 = zero, s1 = zero;
#pragma unroll
      for (int kk = 0; kk < 4; ++kk) {
        s0 = __builtin_amdgcn_mfma_f32_16x16x32_bf16(kf[0][kk], qa[kk], s0, 0, 0, 0);
        s1 = __builtin_amdgcn_mfma_f32_16x16x32_bf16(kf[1][kk], qa[kk], s1, 0, 0, 0);
      }
      float p00 = __expf(s0[0]), p01 = __expf(s0[1]);
      float p02 = __expf(s0[2]), p03 = __expf(s0[3]);
      float p10 = __expf(s1[0]), p11 = __expf(s1[1]);
      float p12 = __expf(s1[2]), p13 = __expf(s1[3]);
      l_acc[qg] += ((p00 + p01) + (p02 + p03)) + ((p10 + p11) + (p12 + p13));
      // store S^T C-layout fragment into [qrow][key] (keys quad*4..+3 and 16+quad*4..+3)
      u32x2 w0, w1;
      w0[0] = pk2(p00, p01); w0[1] = pk2(p02, p03);
      w1[0] = pk2(p10, p11); w1[1] = pk2(p12, p13);
      int off = (qg * 16 + l16) * 20 + quad * 2;
      *(u32x2*)&pw[off]     = w0;
      *(u32x2*)&pw[off + 8] = w1;
    }

    short8 pb[4];
#pragma unroll
    for (int qg = 0; qg < 4; ++qg)
      pb[qg] = *(const short8*)&pw[(qg * 16 + l16) * 20 + quad * 4];  // B-op: [n=qrow][k=key]

#pragma unroll
    for (int ns = 0; ns < 8; ++ns) {
      const short8 vf = *(const short8*)&Vbase[(size_t)(ns * 16 + l16) * 2048 + kb + quad * 8];
#pragma unroll
      for (int qg = 0; qg < 4; ++qg)
        oacc[qg][ns] = __builtin_amdgcn_mfma_f32_16x16x32_bf16(vf, pb[qg], oacc[qg][ns], 0, 0, 0);
    }
  }

#pragma unroll
  for (int qg = 0; qg < 4; ++qg) {
    float l = l_acc[qg];
    l += __shfl_xor(l, 16, 64);
    l += __shfl_xor(l, 32, 64);
    l_acc[qg] = l;
  }
  if (quad == 0) {
#pragma unroll
    for (int qg = 0; qg < 4; ++qg) Lred[wave * 64 + qg * 16 + l16] = l_acc[qg];
  }

  const int tq = tid >> 4;
  const int td = (tid & 15) * 8;
  for (int qg = 0; qg < 4; ++qg) {
    __syncthreads();   // pass 0: Qs/Pbf dead, Lred visible; later: Rbuf free
#pragma unroll
    for (int ns = 0; ns < 8; ++ns)
      *(f32x4*)&Rbuf[(wave * 16 + l16) * 132 + ns * 16 + quad * 4] = oacc[qg][ns];
    __syncthreads();
    float lt = Lred[qg * 16 + tq] + Lred[64 + qg * 16 + tq] +
               Lred[128 + qg * 16 + tq] + Lred[192 + qg * 16 + tq];
    float inv = 1.0f / lt;
    f32x4 sA = zero, sB = zero;
#pragma unroll
    for (int w = 0; w < 4; ++w) {
      sA += *(const f32x4*)&Rbuf[(w * 16 + tq) * 132 + td];
      sB += *(const f32x4*)&Rbuf[(w * 16 + tq) * 132 + td + 4];
    }
    ushort4 o1, o2;
    o1.x = f2b(sA[0] * inv); o1.y = f2b(sA[1] * inv);
    o1.z = f2b(sA[2] * inv); o1.w = f2b(sA[3] * inv);
    o2.x = f2b(sB[0] * inv); o2.y = f2b(sB[1] * inv);
    o2.z = f2b(sB[2] * inv); o2.w = f2b(sB[3] * inv);
    size_t orow = (size_t)(qt * 64 + qg * 16 + tq) * 2048 + head * 128 + td;
    *(ushort4*)&O[orow] = o1;
    *(ushort4*)&O[orow + 4] = o2;
  }
}

// ---------------- Wo GEMM-BT: 128x64 tile, BK=64, fp32 output ----------------
__global__ __launch_bounds__(256) void k_gemm_wo(const ushort_t* __restrict__ A,
                                                 const ushort_t* __restrict__ B,
                                                 float* __restrict__ C) {
  __shared__ ushort_t As[128 * 64];
  __shared__ ushort_t Bs[64 * 64];
  const int tid = threadIdx.x;
  const int lane = tid & 63, wave = tid >> 6;
  const int quad = lane >> 4, l16 = lane & 15;
  const int wm = wave >> 1, wn = wave & 1;
  const size_t row0 = (size_t)blockIdx.y * 128, col0 = (size_t)blockIdx.x * 64;

  f32x4 zero = {0.f, 0.f, 0.f, 0.f};
  f32x4 acc[4][2];
#pragma unroll
  for (int i = 0; i < 4; ++i)
#pragma unroll
    for (int j = 0; j < 2; ++j) acc[i][j] = zero;

  for (int kt = 0; kt < 32; ++kt) {
#pragma unroll
    for (int j2 = 0; j2 < 4; ++j2) {
      int c = tid + 256 * j2;
      int r = c >> 3, p = c & 7;
      LDS_LOAD16(A + (row0 + r) * 2048 + kt * 64 + (p ^ swz8(r)) * 8, &As[c * 8]);
    }
#pragma unroll
    for (int j2 = 0; j2 < 2; ++j2) {
      int c = tid + 256 * j2;
      int r = c >> 3, p = c & 7;
      LDS_LOAD16(B + (col0 + r) * 2048 + kt * 64 + (p ^ swz8(r)) * 8, &Bs[c * 8]);
    }
    __syncthreads();
    short8 a[4][2], b[2][2];
#pragma unroll
    for (int i = 0; i < 4; ++i) {
      int ra = wm * 64 + i * 16 + l16;
#pragma unroll
      for (int kk = 0; kk < 2; ++kk)
        a[i][kk] = *(const short8*)&As[(ra * 8 + ((kk * 4 + quad) ^ swz8(ra))) * 8];
    }
#pragma unroll
    for (int j = 0; j < 2; ++j) {
      int rb = wn * 32 + j * 16 + l16;
#pragma unroll
      for (int kk = 0; kk < 2; ++kk)
        b[j][kk] = *(const short8*)&Bs[(rb * 8 + ((kk * 4 + quad) ^ swz8(rb))) * 8];
    }
#pragma unroll
    for (int kk = 0; kk < 2; ++kk)
#pragma unroll
      for (int i = 0; i < 4; ++i)
#pragma unroll
        for (int j = 0; j < 2; ++j)
          acc[i][j] = __builtin_amdgcn_mfma_f32_16x16x32_bf16(a[i][kk], b[j][kk], acc[i][j], 0, 0, 0);
    __syncthreads();
  }

#pragma unroll
  for (int i = 0; i < 4; ++i)
#pragma unroll
    for (int j = 0; j < 2; ++j)
#pragma unroll
      for (int r = 0; r < 4; ++r) {
        size_t row = row0 + wm * 64 + i * 16 + quad * 4 + r;
        size_t col = col0 + wn * 32 + j * 16 + l16;
        C[row * 2048 + col] = acc[i][j][r];
      }
}

extern "C" void kernel_launch(void* const* d_in, const int* in_sizes, int n_in,
                              void* d_out, int out_size, void* d_ws, size_t ws_size,
                              hipStream_t stream) {
  const float* X  = (const float*)d_in[0];
  const float* wq = (const float*)d_in[1];
  const float* wk = (const float*)d_in[2];
  const float* wv = (const float*)d_in[3];
  const float* wo = (const float*)d_in[4];
  const int*  pos = (const int*)d_in[5];
  float* out = (float*)d_out;

  if (ws_size < 9 * E * sizeof(ushort_t)) return;  // need 72 MB scratch

  ushort_t* Xb  = (ushort_t*)d_ws;
  ushort_t* Wqb = Xb + E;
  ushort_t* Wkb = Xb + 2 * E;
  ushort_t* Wvb = Xb + 3 * E;
  ushort_t* Wob = Xb + 4 * E;
  ushort_t* Qm  = Xb + 5 * E;
  ushort_t* Km  = Xb + 6 * E;
  ushort_t* Vtm = Xb + 7 * E;
  ushort_t* Om  = Xb + 8 * E;

  dim3 b256(256);
  k_cvt5<<<dim3(4096, 5), b256, 0, stream>>>(X, wq, wk, wv, wo, Xb);
  k_gemm_qkv<<<dim3(16, 16, 3), b256, 0, stream>>>(Xb, Wqb, Wkb, Wvb, Qm, Km, Vtm, pos);
  k_attn<<<512, b256, 0, stream>>>(Qm, Km, Vtm, Om);
  k_gemm_wo<<<dim3(32, 16), b256, 0, stream>>>(Om, Wob, out);
}

// Round 7
// 317.656 us; speedup vs baseline: 1.3285x; 1.1494x over previous
//
#include <hip/hip_runtime.h>

typedef unsigned short ushort_t;
typedef unsigned int uint32;
typedef __attribute__((ext_vector_type(8))) short short8;
typedef __attribute__((ext_vector_type(4))) float f32x4;
typedef __attribute__((ext_vector_type(2))) uint32 u32x2;

#define LDS_LOAD16(gptr, lptr)                                                             \
  __builtin_amdgcn_global_load_lds((const __attribute__((address_space(1))) uint32*)(gptr),\
                                   (__attribute__((address_space(3))) uint32*)(lptr),      \
                                   16, 0, 0)

__device__ __forceinline__ ushort_t f2b(float f) {
  uint32 u = __builtin_bit_cast(uint32, f);
  u += 0x7fffu + ((u >> 16) & 1u);   // RNE
  return (ushort_t)(u >> 16);
}
__device__ __forceinline__ uint32 pk2(float a, float b) {
  return (uint32)f2b(a) | ((uint32)f2b(b) << 16);
}
__device__ __forceinline__ int swz8(int r) { return (r ^ (r >> 3)) & 7; }

constexpr size_t E = (size_t)2048 * 2048;

// ---------------- fused fp32 -> bf16 convert (all 5 tensors) ----------------
__global__ __launch_bounds__(256) void k_cvt5(const float* __restrict__ a0, const float* __restrict__ a1,
                                              const float* __restrict__ a2, const float* __restrict__ a3,
                                              const float* __restrict__ a4, ushort_t* __restrict__ out) {
  const float* srcs[5] = {a0, a1, a2, a3, a4};
  const float* s = srcs[blockIdx.y];
  size_t i = ((size_t)blockIdx.x * 256 + threadIdx.x) * 4;
  float4 v = *(const float4*)(s + i);
  ushort4 o;
  o.x = f2b(v.x); o.y = f2b(v.y); o.z = f2b(v.z); o.w = f2b(v.w);
  *(ushort4*)(out + (size_t)blockIdx.y * E + i) = o;
}

// ---------------- fused QKV GEMM-BT, BK=64, fused RoPE epilogue (R4 known-good) ----------------
// z=0 -> Qm (rope + 1/sqrt(dh) scale), z=1 -> Km (rope), z=2 -> Vt (transposed write)
__global__ __launch_bounds__(256) void k_gemm_qkv(const ushort_t* __restrict__ A,
                                                  const ushort_t* __restrict__ B0,
                                                  const ushort_t* __restrict__ B1,
                                                  const ushort_t* __restrict__ B2,
                                                  ushort_t* __restrict__ Qm,
                                                  ushort_t* __restrict__ Km,
                                                  ushort_t* __restrict__ Vt,
                                                  const int* __restrict__ pos) {
  __shared__ ushort_t As[128 * 64];
  __shared__ ushort_t Bs[128 * 64];
  const int tid = threadIdx.x;
  const int lane = tid & 63, wave = tid >> 6;
  const int quad = lane >> 4, l16 = lane & 15;
  const int wm = wave >> 1, wn = wave & 1;
  const int z = blockIdx.z;
  const ushort_t* Bp = (z == 0) ? B0 : (z == 1) ? B1 : B2;
  const size_t row0 = (size_t)blockIdx.y * 128, col0 = (size_t)blockIdx.x * 128;

  int g[4];
#pragma unroll
  for (int j = 0; j < 4; ++j) g[j] = (j & 1) + ((j >> 1) << 2) + wn * 2;  // {0,1,4,5}/{2,3,6,7}

  f32x4 zero = {0.f, 0.f, 0.f, 0.f};
  f32x4 acc[4][4];
#pragma unroll
  for (int i = 0; i < 4; ++i)
#pragma unroll
    for (int j = 0; j < 4; ++j) acc[i][j] = zero;

  for (int kt = 0; kt < 32; ++kt) {
#pragma unroll
    for (int j2 = 0; j2 < 4; ++j2) {
      int c = tid + 256 * j2;            // 1024 chunks of 16B per matrix
      int r = c >> 3, p = c & 7;
      int sc = (p ^ swz8(r)) * 8;
      LDS_LOAD16(A + (row0 + r) * 2048 + kt * 64 + sc, &As[c * 8]);
      LDS_LOAD16(Bp + (col0 + r) * 2048 + kt * 64 + sc, &Bs[c * 8]);
    }
    __syncthreads();
    short8 a[4][2], b[4][2];
#pragma unroll
    for (int i = 0; i < 4; ++i) {
      int ra = wm * 64 + i * 16 + l16;
#pragma unroll
      for (int kk = 0; kk < 2; ++kk)
        a[i][kk] = *(const short8*)&As[(ra * 8 + ((kk * 4 + quad) ^ swz8(ra))) * 8];
    }
#pragma unroll
    for (int j = 0; j < 4; ++j) {
      int rb = g[j] * 16 + l16;
#pragma unroll
      for (int kk = 0; kk < 2; ++kk)
        b[j][kk] = *(const short8*)&Bs[(rb * 8 + ((kk * 4 + quad) ^ swz8(rb))) * 8];
    }
#pragma unroll
    for (int kk = 0; kk < 2; ++kk)
#pragma unroll
      for (int i = 0; i < 4; ++i)
#pragma unroll
        for (int j = 0; j < 4; ++j)
          acc[i][j] = __builtin_amdgcn_mfma_f32_16x16x32_bf16(a[i][kk], b[j][kk], acc[i][j], 0, 0, 0);
    __syncthreads();
  }

  if (z < 2) {
    ushort_t* C = z ? Km : Qm;
    const float mul = z ? 1.0f : 0.08838834764831845f;  // fold 1/sqrt(128) into Q
#pragma unroll
    for (int i = 0; i < 4; ++i)
#pragma unroll
      for (int r = 0; r < 4; ++r) {
        size_t row = row0 + wm * 64 + i * 16 + quad * 4 + r;
        float pt = (float)pos[row];
        size_t rowoff = row * 2048 + col0;
#pragma unroll
        for (int j = 0; j < 2; ++j) {
          int f = g[j] * 16 + l16;   // f in [0,64)
          float ang = pt * __expf(-0.14391156831212787f * (float)f);
          float sn, cs;
          __sincosf(ang, &sn, &cs);
          cs *= mul; sn *= mul;
          float q0 = acc[i][j][r], q1 = acc[i][j + 2][r];
          C[rowoff + f]      = f2b(q0 * cs - q1 * sn);
          C[rowoff + f + 64] = f2b(q1 * cs + q0 * sn);
        }
      }
  } else {
#pragma unroll
    for (int i = 0; i < 4; ++i)
#pragma unroll
      for (int j = 0; j < 4; ++j) {
        size_t col = col0 + g[j] * 16 + l16;
        size_t rowb = row0 + wm * 64 + i * 16 + quad * 4;
        ushort4 ov;
        ov.x = f2b(acc[i][j][0]); ov.y = f2b(acc[i][j][1]);
        ov.z = f2b(acc[i][j][2]); ov.w = f2b(acc[i][j][3]);
        *(ushort4*)&Vt[col * 2048 + rowb] = ov;
      }
  }
}

// ---------------- flash attention: key-split waves, P-transpose via wave-private LDS ----------------
// Q arrives pre-scaled by 1/sqrt(dh). grid 512: 64 q-rows x 16 heads, XCD-clustered.
// __launch_bounds__(256,2) is LOAD-BEARING: 128 AGPR acc + VGPRs must fit 256/wave
// (unified file) for 2 blocks/CU; without it the allocator drops to 1 block/CU (R6: 137us).
__global__ __launch_bounds__(256, 2) void k_attn(const ushort_t* __restrict__ Q,
                                                 const ushort_t* __restrict__ Kg,
                                                 const ushort_t* __restrict__ Vt,
                                                 ushort_t* __restrict__ O) {
  __shared__ uint32 smem[9216 + 256];   // 36 KB (Qs 16K + Pbuf 20K) + Lred 1K
  ushort_t* Qs  = (ushort_t*)smem;      // 64 x 128 bf16, swizzled: chunk c at c ^ (r&15)
  uint32*   Pbf = smem + 4096;          // 4 waves x 64 rows x 20 dwords (80 B stride)
  float*    Lred = (float*)(smem + 9216);  // [wave][qg][l16]
  float*    Rbuf = (float*)smem;        // epilogue alias: [wave][16][132] = 8448 dw <= 9216

  const int tid = threadIdx.x;
  const int lane = tid & 63, wave = tid >> 6;
  const int quad = lane >> 4, l16 = lane & 15;
  const int bid = blockIdx.x;
  const int head = ((bid & 7) << 1) + ((bid >> 3) >> 5);
  const int qt = (bid >> 3) & 31;

#pragma unroll
  for (int j = 0; j < 4; ++j) {
    int s = tid + 256 * j;
    int r = s >> 4, p = s & 15;
    LDS_LOAD16(Q + (size_t)(qt * 64 + r) * 2048 + head * 128 + ((p ^ (r & 15)) * 8), &Qs[s * 8]);
  }
  __syncthreads();

  f32x4 zero = {0.f, 0.f, 0.f, 0.f};
  f32x4 oacc[4][8];
#pragma unroll
  for (int qg = 0; qg < 4; ++qg)
#pragma unroll
    for (int ns = 0; ns < 8; ++ns) oacc[qg][ns] = zero;
  float l_acc[4] = {0.f, 0.f, 0.f, 0.f};

  const ushort_t* Kbase = Kg + (size_t)head * 128;
  const ushort_t* Vbase = Vt + (size_t)head * 128 * 2048;
  uint32* pw = Pbf + wave * 1280;

  for (int it = 0; it < 16; ++it) {
    const int kb = it * 128 + wave * 32;

    short8 kf[2][4];
#pragma unroll
    for (int kg = 0; kg < 2; ++kg)
#pragma unroll
      for (int kk = 0; kk < 4; ++kk)
        kf[kg][kk] = *(const short8*)&Kbase[(size_t)(kb + kg * 16 + l16) * 2048 + kk * 32 + quad * 8];

#pragma unroll
    for (int qg = 0; qg < 4; ++qg) {
      short8 qa[4];
#pragma unroll
      for (int kk = 0; kk < 4; ++kk)
        qa[kk] = *(const short8*)&Qs[((qg * 16 + l16) * 16 + ((kk * 4 + quad) ^ l16)) * 8];
      f32x4 s0 = zero, s1 = zero;
#pragma unroll
      for (int kk = 0; kk < 4; ++kk) {
        s0 = __builtin_amdgcn_mfma_f32_16x16x32_bf16(kf[0][kk], qa[kk], s0, 0, 0, 0);
        s1 = __builtin_amdgcn_mfma_f32_16x16x32_bf16(kf[1][kk], qa[kk], s1, 0, 0, 0);
      }
      float p00 = __expf(s0[0]), p01 = __expf(s0[1]);
      float p02 = __expf(s0[2]), p03 = __expf(s0[3]);
      float p10 = __expf(s1[0]), p11 = __expf(s1[1]);
      float p12 = __expf(s1[2]), p13 = __expf(s1[3]);
      l_acc[qg] += ((p00 + p01) + (p02 + p03)) + ((p10 + p11) + (p12 + p13));
      // store S^T C-layout fragment into [qrow][key] (keys quad*4..+3 and 16+quad*4..+3)
      u32x2 w0, w1;
      w0[0] = pk2(p00, p01); w0[1] = pk2(p02, p03);
      w1[0] = pk2(p10, p11); w1[1] = pk2(p12, p13);
      int off = (qg * 16 + l16) * 20 + quad * 2;
      *(u32x2*)&pw[off]     = w0;
      *(u32x2*)&pw[off + 8] = w1;
    }

    short8 pb[4];
#pragma unroll
    for (int qg = 0; qg < 4; ++qg)
      pb[qg] = *(const short8*)&pw[(qg * 16 + l16) * 20 + quad * 4];  // B-op: [n=qrow][k=key]

#pragma unroll
    for (int ns = 0; ns < 8; ++ns) {
      const short8 vf = *(const short8*)&Vbase[(size_t)(ns * 16 + l16) * 2048 + kb + quad * 8];
#pragma unroll
      for (int qg = 0; qg < 4; ++qg)
        oacc[qg][ns] = __builtin_amdgcn_mfma_f32_16x16x32_bf16(vf, pb[qg], oacc[qg][ns], 0, 0, 0);
    }
  }

#pragma unroll
  for (int qg = 0; qg < 4; ++qg) {
    float l = l_acc[qg];
    l += __shfl_xor(l, 16, 64);
    l += __shfl_xor(l, 32, 64);
    l_acc[qg] = l;
  }
  if (quad == 0) {
#pragma unroll
    for (int qg = 0; qg < 4; ++qg) Lred[wave * 64 + qg * 16 + l16] = l_acc[qg];
  }

  const int tq = tid >> 4;
  const int td = (tid & 15) * 8;
  for (int qg = 0; qg < 4; ++qg) {
    __syncthreads();   // pass 0: Qs/Pbf dead, Lred visible; later: Rbuf free
#pragma unroll
    for (int ns = 0; ns < 8; ++ns)
      *(f32x4*)&Rbuf[(wave * 16 + l16) * 132 + ns * 16 + quad * 4] = oacc[qg][ns];
    __syncthreads();
    float lt = Lred[qg * 16 + tq] + Lred[64 + qg * 16 + tq] +
               Lred[128 + qg * 16 + tq] + Lred[192 + qg * 16 + tq];
    float inv = 1.0f / lt;
    f32x4 sA = zero, sB = zero;
#pragma unroll
    for (int w = 0; w < 4; ++w) {
      sA += *(const f32x4*)&Rbuf[(w * 16 + tq) * 132 + td];
      sB += *(const f32x4*)&Rbuf[(w * 16 + tq) * 132 + td + 4];
    }
    ushort4 o1, o2;
    o1.x = f2b(sA[0] * inv); o1.y = f2b(sA[1] * inv);
    o1.z = f2b(sA[2] * inv); o1.w = f2b(sA[3] * inv);
    o2.x = f2b(sB[0] * inv); o2.y = f2b(sB[1] * inv);
    o2.z = f2b(sB[2] * inv); o2.w = f2b(sB[3] * inv);
    size_t orow = (size_t)(qt * 64 + qg * 16 + tq) * 2048 + head * 128 + td;
    *(ushort4*)&O[orow] = o1;
    *(ushort4*)&O[orow + 4] = o2;
  }
}

// ---------------- Wo GEMM-BT, split-K=2: 128x128 tile, BK=64, fp32 partials ----------------
// grid (16,16,2): z selects K-half [z*1024, z*1024+1024). Partials to P[z*E + ...].
__global__ __launch_bounds__(256) void k_gemm_wo_sk(const ushort_t* __restrict__ A,
                                                    const ushort_t* __restrict__ B,
                                                    float* __restrict__ P) {
  __shared__ ushort_t As[128 * 64];
  __shared__ ushort_t Bs[128 * 64];
  const int tid = threadIdx.x;
  const int lane = tid & 63, wave = tid >> 6;
  const int quad = lane >> 4, l16 = lane & 15;
  const int wm = wave >> 1, wn = wave & 1;
  const size_t row0 = (size_t)blockIdx.y * 128, col0 = (size_t)blockIdx.x * 128;
  const int k0 = blockIdx.z * 1024;
  float* Pz = P + (size_t)blockIdx.z * E;

  f32x4 zero = {0.f, 0.f, 0.f, 0.f};
  f32x4 acc[4][4];
#pragma unroll
  for (int i = 0; i < 4; ++i)
#pragma unroll
    for (int j = 0; j < 4; ++j) acc[i][j] = zero;

  for (int kt = 0; kt < 16; ++kt) {
#pragma unroll
    for (int j2 = 0; j2 < 4; ++j2) {
      int c = tid + 256 * j2;
      int r = c >> 3, p = c & 7;
      int sc = (p ^ swz8(r)) * 8;
      LDS_LOAD16(A + (row0 + r) * 2048 + k0 + kt * 64 + sc, &As[c * 8]);
      LDS_LOAD16(B + (col0 + r) * 2048 + k0 + kt * 64 + sc, &Bs[c * 8]);
    }
    __syncthreads();
    short8 a[4][2], b[4][2];
#pragma unroll
    for (int i = 0; i < 4; ++i) {
      int ra = wm * 64 + i * 16 + l16;
#pragma unroll
      for (int kk = 0; kk < 2; ++kk)
        a[i][kk] = *(const short8*)&As[(ra * 8 + ((kk * 4 + quad) ^ swz8(ra))) * 8];
    }
#pragma unroll
    for (int j = 0; j < 4; ++j) {
      int rb = wn * 64 + j * 16 + l16;
#pragma unroll
      for (int kk = 0; kk < 2; ++kk)
        b[j][kk] = *(const short8*)&Bs[(rb * 8 + ((kk * 4 + quad) ^ swz8(rb))) * 8];
    }
#pragma unroll
    for (int kk = 0; kk < 2; ++kk)
#pragma unroll
      for (int i = 0; i < 4; ++i)
#pragma unroll
        for (int j = 0; j < 4; ++j)
          acc[i][j] = __builtin_amdgcn_mfma_f32_16x16x32_bf16(a[i][kk], b[j][kk], acc[i][j], 0, 0, 0);
    __syncthreads();
  }

#pragma unroll
  for (int i = 0; i < 4; ++i)
#pragma unroll
    for (int j = 0; j < 4; ++j)
#pragma unroll
      for (int r = 0; r < 4; ++r) {
        size_t row = row0 + wm * 64 + i * 16 + quad * 4 + r;
        size_t col = col0 + wn * 64 + j * 16 + l16;
        Pz[row * 2048 + col] = acc[i][j][r];
      }
}

// ---------------- split-K reduce: out = P0 + P1 (fp32) ----------------
__global__ __launch_bounds__(256) void k_red(const float* __restrict__ P, float* __restrict__ out) {
  size_t i = ((size_t)blockIdx.x * 256 + threadIdx.x) * 4;
  f32x4 a = *(const f32x4*)(P + i);
  f32x4 b = *(const f32x4*)(P + E + i);
  *(f32x4*)(out + i) = a + b;
}

extern "C" void kernel_launch(void* const* d_in, const int* in_sizes, int n_in,
                              void* d_out, int out_size, void* d_ws, size_t ws_size,
                              hipStream_t stream) {
  const float* X  = (const float*)d_in[0];
  const float* wq = (const float*)d_in[1];
  const float* wk = (const float*)d_in[2];
  const float* wv = (const float*)d_in[3];
  const float* wo = (const float*)d_in[4];
  const int*  pos = (const int*)d_in[5];
  float* out = (float*)d_out;

  if (ws_size < 9 * E * sizeof(ushort_t)) return;  // need 72 MB scratch

  ushort_t* Xb  = (ushort_t*)d_ws;
  ushort_t* Wqb = Xb + E;
  ushort_t* Wkb = Xb + 2 * E;
  ushort_t* Wvb = Xb + 3 * E;
  ushort_t* Wob = Xb + 4 * E;
  ushort_t* Qm  = Xb + 5 * E;
  ushort_t* Km  = Xb + 6 * E;
  ushort_t* Vtm = Xb + 7 * E;
  ushort_t* Om  = Xb + 8 * E;
  // After k_attn, Xb..Wvb (4E ushorts = 32 MB) are dead: reuse as 2x fp32 partial planes.
  float* Pf = (float*)Xb;   // P0 = [0,E) floats, P1 = [E,2E) floats

  dim3 b256(256);
  k_cvt5<<<dim3(4096, 5), b256, 0, stream>>>(X, wq, wk, wv, wo, Xb);
  k_gemm_qkv<<<dim3(16, 16, 3), b256, 0, stream>>>(Xb, Wqb, Wkb, Wvb, Qm, Km, Vtm, pos);
  k_attn<<<512, b256, 0, stream>>>(Qm, Km, Vtm, Om);
  k_gemm_wo_sk<<<dim3(16, 16, 2), b256, 0, stream>>>(Om, Wob, Pf);
  k_red<<<4096, b256, 0, stream>>>(Pf, out);
}